// Round 4
// baseline (129.264 us; speedup 1.0000x reference)
//
#include <hip/hip_runtime.h>

// OESNN_SEPhIA_MultiTiled2: 32-step recurrent SNN, B=8192.
// R6: R4's non-redundant role-split + cross-t software pipeline + 4 waves/SIMD.
// Evidence: R2/R5 at 1 wave/SIMD stall ~83% on a CHAIN of short latencies
// (weight reads, recurrent bpermute gather, store drain) -- only TLP hides
// that. R3 (4 waves/SIMD) proved occupancy/VALUBusy rise but paid 4.6x
// redundant issue; R4 cut redundancy via role-split but serialized
// L0 -> ds_write -> lgkmcnt -> L1 inside each iteration (VALUBusy 30%).
// R6 keeps R4's mapping (32 lanes/elem: lanes 0..17 own one L0 channel,
// 18..25 own one L1 output) and pipelines: phase p runs L1(p-1) from the
// LDS slot written at phase p-1 concurrently with L0(p) -> slot[p&1].
// Same-wave DS is in-order (R4-verified), no barriers, ping-pong slots.
// Per-lane weights = 36 regs, x prefetch depth-2 -> fits 128 VGPR ->
// __launch_bounds__(256,4) = 4 waves/SIMD, 4096 waves.
// Numerics are op-for-op identical to the PASSING R4 kernel: p = x*1e-4
// single rounding, ascending-w single-accumulator fma chains, select-based
// LIF, pw values moved verbatim through LDS.

namespace {
constexpr int Tn = 32;
constexpr int Bn = 8192;
constexpr int O_PW = 0;                       // spks0 (= pw0) [T,B,18]
constexpr int O_S1 = Tn * Bn * 18;            // spks1 [T,B,8]
constexpr int O_M0 = O_S1 + Tn * Bn * 8;      // mems0 [T,B,18]
constexpr int O_M1 = O_M0 + Tn * Bn * 18;     // mems1 [T,B,8]
}

__global__ __launch_bounds__(256, 4)
void oesnn_kernel(const float* __restrict__ x_in,
                  const float* __restrict__ W0g,   // [2,18,18]
                  const float* __restrict__ d0g,   // [2,9]
                  const float* __restrict__ W1g,   // [1,18,16]
                  const float* __restrict__ d1g,   // [1,8]
                  const float* __restrict__ peakg, // [36]
                  float* __restrict__ out)
{
    const int tid = blockIdx.x * 256 + threadIdx.x;
    const int b   = tid >> 5;                 // batch element (32 lanes/elem)
    const int g   = tid & 31;                 // lane within batch group
    const int wv  = threadIdx.x >> 6;         // wave within block 0..3
    const int eh  = (threadIdx.x >> 5) & 1;   // element half within wave
    const bool isL0 = (g < 18);
    const bool isL1 = (g >= 18) && (g < 26);

    // pw handoff: per-wave, per-parity, per-element 18-float slot.
    // Stride 20 dwords = 80 B so each slot base is 16B-aligned for b128 reads.
    __shared__ float pwsh[4][2][2][20];

    // ---------------- per-lane weight preload into registers ----------------
    // L0 lanes: W0 even/odd columns of channel g (36 regs). L1 lanes: W1
    // even/odd columns of output g-18 (same arrays -> union footprint 36).
    float wA[18], wB[18];
    float dd = 0.f, pon = 0.f, poff = 0.f;
    const int tl = isL0 ? (g / 9) : 0;        // clamped: keeps x addrs in-bounds

    if (isL0) {
        const int jc = g % 9;
        dd = d0g[tl * 9 + jc];
        #pragma unroll
        for (int w = 0; w < 18; ++w) {
            const float2 p = *(const float2*)(W0g + ((tl * 18 + w) * 18 + 2 * jc));
            wA[w] = p.x;
            wB[w] = p.y;
        }
        // pw0 takes exactly two values per channel: precompute via the
        // reference's complex-division -> abs -> square path (verbatim R4).
        const int c = g;
        const float wl    = 1550.0f + 0.8f * (float)c;
        const float halfw = 0.5f * (wl * 1e3f / 15000.0f);
        const float amp   = sqrtf((exp10f(peakg[c] / 10.0f) / 1000.0f) * 1e6f);
        {   // spike = 0: lo = (0.1 + 0i)/(1 + 0i) * amp
            const float lr = 0.1f * amp;
            const float a  = sqrtf(lr * lr);
            poff = a * a;
        }
        {   // spike = 1: delta = -250 / (0.5*fwhm)
            const float delta = -250.0f / halfw;
            const float den = fmaf(delta, delta, 1.0f);
            const float qr  = fmaf(delta, delta, 0.1f) / den;     // (g + d^2)/den
            const float qi  = (delta - 0.1f * delta) / den;       // (d - g*d)/den
            const float lr = qr * amp, li = qi * amp;
            const float a  = sqrtf(fmaf(lr, lr, li * li));
            pon = a * a;
        }
    } else {
        const int o = (g < 26) ? (g - 18) : 7;   // clamp idle lanes 26..31
        dd = d1g[o];
        #pragma unroll
        for (int w = 0; w < 18; ++w) {
            const float2 p = *(const float2*)(W1g + w * 16 + 2 * o);  // 8B-aligned
            wA[w] = p.x;
            wB[w] = p.y;
        }
    }

    // ---------------- state & pointers ----------------
    float mem0 = 0.f;   // L0 lanes: channel membrane
    float mem1 = 0.f;   // L1 lanes: output membrane

    const float* xb = x_in + (size_t)b * 36 + tl * 18;   // in-bounds for ALL lanes
    float* opw = out + O_PW + (size_t)b * 18 + g;        // L0 stores (t = even base)
    float* om0 = out + O_M0 + (size_t)b * 18 + g;
    const int o1 = isL1 ? (g - 18) : 0;
    float* os1 = out + O_S1 + (size_t)b * 8 + o1;        // points at t1 = t2
    float* om1 = out + O_M1 + (size_t)b * 8 + o1;

    // depth-2 x prefetch (unguarded: tl-clamped addresses are always valid)
    float2 xvA[9], xvB[9];
    {
        const float2* s0 = (const float2*)(xb);
        const float2* s1 = (const float2*)(xb + (size_t)Bn * 36);
        #pragma unroll
        for (int k = 0; k < 9; ++k) { xvA[k] = s0[k]; xvB[k] = s1[k]; }
    }

    // ---- L1 phase for timestep t1: read pw from parity `parr`, LIF, store ----
    auto l1phase = [&](int parr, float* os1p, float* om1p) {
        if (isL1) {
            const float4 qa = *(const float4*)&pwsh[wv][parr][eh][0];
            const float4 qb = *(const float4*)&pwsh[wv][parr][eh][4];
            const float4 qc = *(const float4*)&pwsh[wv][parr][eh][8];
            const float4 qd = *(const float4*)&pwsh[wv][parr][eh][12];
            const float2 qe = *(const float2*)&pwsh[wv][parr][eh][16];
            const float pwall[18] = {qa.x, qa.y, qa.z, qa.w,
                                     qb.x, qb.y, qb.z, qb.w,
                                     qc.x, qc.y, qc.z, qc.w,
                                     qd.x, qd.y, qd.z, qd.w,
                                     qe.x, qe.y};
            float i1e = 0.f, i1o = 0.f;
            #pragma unroll
            for (int c = 0; c < 18; ++c) {
                i1e = fmaf(pwall[c], wA[c], i1e);
                i1o = fmaf(pwall[c], wB[c], i1o);
            }
            const float c1 = (i1e - i1o) * dd;
            const float m3 = (mem1 > 0.25f) ? 0.0f : fmaf(0.95f, mem1, c1);
            mem1 = m3;
            *os1p = (m3 > 0.25f) ? 1.0f : 0.0f;
            *om1p = m3;
        }
    };

    // ---- L0 phase for timestep t: consume xv, refill xv <- x(t+2), dot,
    // LIF, store, publish pw to parity `parw` ----
    auto l0phase = [&](float2 (&xv)[9], int t, int parw,
                       float* opwp, float* om0p) {
        // p = x * 1e-4, rounded once (identical arithmetic to R4)
        float p[18];
        #pragma unroll
        for (int k = 0; k < 9; ++k) {
            p[2 * k]     = xv[k].x * 1e-4f;
            p[2 * k + 1] = xv[k].y * 1e-4f;
        }
        if (t + 2 < Tn) {   // refill freed buffer two steps ahead
            const float2* s = (const float2*)(xb + (size_t)(t + 2) * Bn * 36);
            #pragma unroll
            for (int k = 0; k < 9; ++k) xv[k] = s[k];
        }
        if (isL0) {
            float se = 0.f, so = 0.f;
            #pragma unroll
            for (int w = 0; w < 18; ++w) {
                se = fmaf(p[w], wA[w], se);
                so = fmaf(p[w], wB[w], so);
            }
            const float c0 = (se - so) * dd;
            const float m2 = (mem0 > 0.55f) ? 0.0f : fmaf(0.95f, mem0, c0);
            mem0 = m2;
            const float pw = (m2 > 0.55f) ? pon : poff;
            *opwp = pw;
            *om0p = m2;
            pwsh[wv][parw][eh][g] = pw;   // same-wave in-order DS handoff
        }
    };

    #pragma unroll 1
    for (int t2 = 0; t2 < Tn; t2 += 2) {
        // phase t2 (even): L1 consumes pw(t2-1) from parity 1, L0 writes par 0
        if (t2 > 0) l1phase(1, os1 - Bn * 8, om1 - Bn * 8);
        l0phase(xvA, t2, 0, opw, om0);
        // phase t2+1 (odd): L1 consumes pw(t2) from parity 0, L0 writes par 1
        l1phase(0, os1, om1);
        l0phase(xvB, t2 + 1, 1, opw + (size_t)Bn * 18, om0 + (size_t)Bn * 18);

        opw += 2 * (size_t)Bn * 18;
        om0 += 2 * (size_t)Bn * 18;
        os1 += 2 * (size_t)Bn * 8;
        om1 += 2 * (size_t)Bn * 8;
    }
    // drain: L1 for t=31 (pw written at odd phase t=31 -> parity 1)
    l1phase(1, os1 - Bn * 8, om1 - Bn * 8);
}

extern "C" void kernel_launch(void* const* d_in, const int* in_sizes, int n_in,
                              void* d_out, int out_size, void* d_ws, size_t ws_size,
                              hipStream_t stream) {
    (void)in_sizes; (void)n_in; (void)out_size; (void)d_ws; (void)ws_size;
    const float* x  = (const float*)d_in[0];
    const float* W0 = (const float*)d_in[1];
    const float* d0 = (const float*)d_in[2];
    const float* W1 = (const float*)d_in[3];
    const float* d1 = (const float*)d_in[4];
    const float* pk = (const float*)d_in[5];
    float* out = (float*)d_out;

    dim3 grid(Bn * 32 / 256), block(256);   // 262144 threads = 4096 waves
    hipLaunchKernelGGL(oesnn_kernel, grid, block, 0, stream,
                       x, W0, d0, W1, d1, pk, out);
}

// Round 5
// 127.687 us; speedup vs baseline: 1.0124x; 1.0124x over previous
//
#include <hip/hip_runtime.h>

// OESNN_SEPhIA_MultiTiled2: 32-step recurrent SNN, B=8192.
// R7: pair-split of the verified R2 structure. Evidence R2/R3/R5/R6: the
// dominant stall is per-iteration reload of weights (compiler demotes them
// whenever pressure > ~120 regs: R2 VGPR=120<190 needed, R3=48, R6=64) or the
// equivalent dependent ds_read chain (R5, ~120cyc x 27 reads == its 3000cyc
// wall). Masked role-splits (R4/R6) waste issue. Fix: keep R2's UNIFORM
// per-lane code path but split each R2 lane across a lane PAIR: even lane
// owns even weight columns (se, i1e), odd lane owns odd columns (so, i1o),
// partial sums exchanged with one shfl_xor(1) per neuron. Per-lane weight
// regs 144 -> 72 (total live ~150: no spill at the 256-VGPR / 2-waves-per-EU
// cap), 16 lanes/elem -> 2048 waves = 2 waves/SIMD, all lanes uniformly busy.
// Numerics bit-identical to R2: p = x*1e-4 single rounding; each accumulator
// (se/so/i1e/i1o) is the same ascending-w single-accumulator fma chain, just
// computed on its own lane; c = (se-so)*dd same op; select-based LIF; pw
// moved by shfl (pure selection).

namespace {
constexpr int Tn = 32;
constexpr int Bn = 8192;
constexpr int O_PW = 0;                       // spks0 (= pw0) [T,B,18]
constexpr int O_S1 = Tn * Bn * 18;            // spks1 [T,B,8]
constexpr int O_M0 = O_S1 + Tn * Bn * 8;      // mems0 [T,B,18]
constexpr int O_M1 = O_M0 + Tn * Bn * 18;     // mems1 [T,B,8]
}

__global__ __launch_bounds__(256, 2)
void oesnn_kernel(const float* __restrict__ x_in,
                  const float* __restrict__ W0g,   // [2,18,18]
                  const float* __restrict__ d0g,   // [2,9]
                  const float* __restrict__ W1g,   // [1,18,16]
                  const float* __restrict__ d1g,   // [1,8]
                  const float* __restrict__ peakg, // [36]
                  float* __restrict__ out)
{
    const int lt  = threadIdx.x & 63;         // lane in wave
    const int tid = blockIdx.x * 256 + threadIdx.x;
    const int b   = tid >> 4;                 // batch element (16 lanes/elem)
    const int h   = tid & 15;                 // lane within batch group
    const int sub = h >> 1;                   // R2's sub (0..7)
    const int par = h & 1;                    // 0: even cols, 1: odd cols
    const int tl  = sub >> 2;                 // layer-0 tile (0/1)
    const int q   = sub & 3;                  // lane-pair within tile
    const int j0  = (q == 0) ? 0 : (2 * q + 1);   // first in-tile channel
    const int nj  = (q == 0) ? 3 : 2;             // real channel count (pad to 3)

    // ---------------- per-lane weight preload into registers ----------------
    // ww[j][w] = W0[tl][w][2*jc + par] : this lane's half-column of chan j.
    // w1[w]    = W1[w][2*sub + par]    : this lane's half-column of output sub.
    float ww[3][18], w1[18];
    float dd0[3], pon[3], poff[3];
    #pragma unroll
    for (int j = 0; j < 3; ++j) {
        const int jc = (j < nj) ? (j0 + j) : j0;   // clamped dup stays in-pair
        dd0[j] = d0g[tl * 9 + jc];
        #pragma unroll
        for (int w = 0; w < 18; ++w)
            ww[j][w] = W0g[(tl * 18 + w) * 18 + 2 * jc + par];
        // pw0 takes exactly two values per channel: precompute via the
        // reference's complex-division -> abs -> square path (verbatim R2).
        const int c = tl * 9 + jc;
        const float wl    = 1550.0f + 0.8f * (float)c;
        const float halfw = 0.5f * (wl * 1e3f / 15000.0f);
        const float amp   = sqrtf((exp10f(peakg[c] / 10.0f) / 1000.0f) * 1e6f);
        {   // spike = 0: lo = (0.1 + 0i)/(1 + 0i) * amp
            const float lr = 0.1f * amp;
            const float a  = sqrtf(lr * lr);
            poff[j] = a * a;
        }
        {   // spike = 1: delta = -250 / (0.5*fwhm)
            const float delta = -250.0f / halfw;
            const float den = fmaf(delta, delta, 1.0f);
            const float qr  = fmaf(delta, delta, 0.1f) / den;     // (g + d^2)/den
            const float qi  = (delta - 0.1f * delta) / den;       // (d - g*d)/den
            const float lr = qr * amp, li = qi * amp;
            const float a  = sqrtf(fmaf(lr, lr, li * li));
            pon[j] = a * a;
        }
    }
    #pragma unroll
    for (int w = 0; w < 18; ++w)
        w1[w] = W1g[w * 16 + 2 * sub + par];
    const float dd1 = d1g[sub];

    // ---------------- state & pointers ----------------
    float mem0[3] = {0.f, 0.f, 0.f};   // identical on both pair lanes
    float mem1 = 0.f;

    const float* xp = x_in + (size_t)b * 36 + tl * 18;
    float* opw = out + O_PW + (size_t)b * 18 + tl * 9 + j0;   // even lane stores
    float* om0 = out + O_M0 + (size_t)b * 18 + tl * 9 + j0;   // odd lane stores
    float* os1 = out + O_S1 + (size_t)b * 8 + sub;            // even lane stores
    float* om1 = out + O_M1 + (size_t)b * 8 + sub;            // odd lane stores

    // prefetch t=0 inputs (18 floats = 9x float2, 8B-aligned)
    float2 xv[9];
    #pragma unroll
    for (int k = 0; k < 9; ++k) xv[k] = *(const float2*)(xp + 2 * k);

    const int base16 = lt & ~15;   // first lane of this element's 16-lane group

    #pragma unroll 1
    for (int t = 0; t < Tn; ++t) {
        // unpack current x, scale to optical power (reference: p_in = x * 1e-4)
        float p[18];
        #pragma unroll
        for (int k = 0; k < 9; ++k) {
            p[2 * k]     = xv[k].x * 1e-4f;
            p[2 * k + 1] = xv[k].y * 1e-4f;
        }
        // prefetch next timestep while computing this one
        xp += Bn * 36;
        if (t < Tn - 1) {
            #pragma unroll
            for (int k = 0; k < 9; ++k) xv[k] = *(const float2*)(xp + 2 * k);
        }

        // ---- layer 0: this lane's half-column dot, exchange, LIF, MRR ----
        float pwv[3];
        #pragma unroll
        for (int j = 0; j < 3; ++j) {
            float s = 0.f;
            #pragma unroll
            for (int w = 0; w < 18; ++w)
                s = fmaf(p[w], ww[j][w], s);      // ascending w, single acc
            const float o = __shfl_xor(s, 1, 64); // partner's half-sum
            const float se = par ? o : s;
            const float so = par ? s : o;
            const float c0 = (se - so) * dd0[j];  // identical on both lanes
            const float m  = mem0[j];
            const float m2 = (m > 0.55f) ? 0.0f : fmaf(0.95f, m, c0);
            mem0[j] = m2;
            pwv[j]  = (m2 > 0.55f) ? pon[j] : poff[j];
        }

        // store pw0 (even lane) / mem0 (odd lane); guard dup channel
        #pragma unroll
        for (int j = 0; j < 3; ++j) {
            if (j < nj) {
                if (par == 0) opw[j] = pwv[j];
                else          om0[j] = mem0[j];
            }
        }

        // ---- layer 1: gather 18 pw (from even lane of owner pair), dot ----
        float i1 = 0.f;
        #pragma unroll
        for (int c = 0; c < 18; ++c) {
            const int tlc = c / 9, jc2 = c % 9;
            const int qo  = (jc2 < 3) ? 0 : ((jc2 - 1) / 2);   // owner pair-in-tile
            const int st  = (qo == 0) ? 0 : (2 * qo + 1);
            const int r   = jc2 - st;                          // owner's reg index
            const float gp = __shfl(pwv[r], base16 + 2 * (tlc * 4 + qo), 64);
            i1 = fmaf(gp, w1[c], i1);             // ascending c, single acc
        }
        const float oi = __shfl_xor(i1, 1, 64);
        const float i1e = par ? oi : i1;
        const float i1o = par ? i1 : oi;
        const float c1 = (i1e - i1o) * dd1;       // identical on both lanes
        const float m  = mem1;
        const float m3 = (m > 0.25f) ? 0.0f : fmaf(0.95f, m, c1);
        mem1 = m3;
        if (par == 0) *os1 = (m3 > 0.25f) ? 1.0f : 0.0f;
        else          *om1 = m3;

        opw += Bn * 18;
        om0 += Bn * 18;
        os1 += Bn * 8;
        om1 += Bn * 8;
    }
}

extern "C" void kernel_launch(void* const* d_in, const int* in_sizes, int n_in,
                              void* d_out, int out_size, void* d_ws, size_t ws_size,
                              hipStream_t stream) {
    (void)in_sizes; (void)n_in; (void)out_size; (void)d_ws; (void)ws_size;
    const float* x  = (const float*)d_in[0];
    const float* W0 = (const float*)d_in[1];
    const float* d0 = (const float*)d_in[2];
    const float* W1 = (const float*)d_in[3];
    const float* d1 = (const float*)d_in[4];
    const float* pk = (const float*)d_in[5];
    float* out = (float*)d_out;

    dim3 grid(Bn * 16 / 256), block(256);   // 131072 threads = 2048 waves
    hipLaunchKernelGGL(oesnn_kernel, grid, block, 0, stream,
                       x, W0, d0, W1, d1, pk, out);
}